// Round 1
// 1646.121 us; speedup vs baseline: 1.2866x; 1.2866x over previous
//
#include <hip/hip_runtime.h>
#include <math.h>

#define B_    256
#define T_    512
#define TH    514          // T + 2 halo rows
#define CP    320          // padded channel stride (both Cin and Cout)
#define COUT  320
#define NSUBJ 4
#define XPAD  36           // LDS row stride in u16: 72B = 18 banks, gcd(18,32)=2 -> conflict-free b128

typedef unsigned int u32;
typedef unsigned short u16;

typedef __bf16 bf16x8 __attribute__((ext_vector_type(8)));
typedef float  f32x16 __attribute__((ext_vector_type(16)));

union FragU { uint4 u4; bf16x8 v; };

__device__ __forceinline__ float bf2f(u16 u) {
    union { u32 i; float f; } v; v.i = ((u32)u) << 16; return v.f;
}
__device__ __forceinline__ u16 f2bf(float f) {
    union { float ff; u32 i; } v; v.ff = f;
    u32 x = v.i;
    x += 0x7fffu + ((x >> 16) & 1u);   // RNE
    return (u16)(x >> 16);
}
__device__ __forceinline__ float2 bfp2(u32 u) {
    float2 r;
    r.x = bf2f((u16)(u & 0xffffu));
    r.y = bf2f((u16)(u >> 16));
    return r;
}
__device__ __forceinline__ float gelu_exact(float x) {
    return 0.5f * x * (1.0f + erff(x * 0.70710678118654752440f));
}
__device__ __forceinline__ bf16x8 ldfrag(const u16* p) {
    FragU f; f.u4 = *(const uint4*)p; return f.v;
}

// ---------------------------------------------------------------------------
// prep_w: fp32 [co][Cin][3] -> bf16 [tap][co][CP] (ci >= Cin zeroed)
// ---------------------------------------------------------------------------
__global__ void prep_w(const float* __restrict__ w, u16* __restrict__ wb, int Cin) {
    const int idx = blockIdx.x * 256 + threadIdx.x;
    if (idx >= 3 * CP * CP) return;
    const int tap = idx / (CP * CP);
    const int r   = idx - tap * CP * CP;
    const int co  = r / CP;
    const int ci  = r - co * CP;
    const float v = (ci < Cin) ? w[((size_t)co * Cin + ci) * 3 + tap] : 0.f;
    wb[idx] = f2bf(v);
}

// zero halo rows (t=-1 and t=T) of the act buffer [B][TH][CP]
__global__ void zero_halo(u16* __restrict__ xh) {
    const int idx = blockIdx.x * 256 + threadIdx.x;   // 20480 uint4 total
    const int i8 = idx * 8;
    const int b = i8 / (2 * CP);
    const int r = i8 - b * 2 * CP;
    const int row = (r < CP) ? 0 : (TH - 1);
    const int c   = (r < CP) ? r : r - CP;
    *(uint4*)(xh + ((size_t)b * TH + row) * CP + c) = make_uint4(0u, 0u, 0u, 0u);
}

// zero the BN partial-sum buffers (p1,p2 contiguous: 2*B_*COUT floats)
__global__ void zero_p(float4* __restrict__ p) {
    p[(size_t)blockIdx.x * 256 + threadIdx.x] = make_float4(0.f, 0.f, 0.f, 0.f);
}

// prep_x: X fp32 [b][271][512] -> act bf16 [b][1+t][ci] (ci>=271 zero)
__global__ __launch_bounds__(256) void prep_x(
    const float* __restrict__ X, u16* __restrict__ xh) {
    __shared__ float Lt[64][65];
    const int t0 = blockIdx.x * 64, c0 = blockIdx.y * 64, b = blockIdx.z;
    {
        const int cr = threadIdx.x >> 2, tq = (threadIdx.x & 3) * 16;
        if (c0 + cr < 271) {
            const float* xp = X + ((size_t)b * 271 + c0 + cr) * 512 + t0 + tq;
            #pragma unroll
            for (int k = 0; k < 16; k += 4) {
                const float4 v = *(const float4*)(xp + k);
                Lt[cr][tq + k]     = v.x;
                Lt[cr][tq + k + 1] = v.y;
                Lt[cr][tq + k + 2] = v.z;
                Lt[cr][tq + k + 3] = v.w;
            }
        } else {
            #pragma unroll
            for (int k = 0; k < 16; ++k) Lt[cr][tq + k] = 0.f;
        }
    }
    __syncthreads();
    {
        const int tr = threadIdx.x >> 2, cq = (threadIdx.x & 3) * 16;
        u16 tmp[16];
        #pragma unroll
        for (int k = 0; k < 16; ++k) tmp[k] = f2bf(Lt[cq + k][tr]);
        u16* op = xh + ((size_t)b * TH + 1 + t0 + tr) * CP + c0 + cq;
        *(uint4*)op       = *(const uint4*)&tmp[0];
        *(uint4*)(op + 8) = *(const uint4*)&tmp[8];
    }
}

// ---------------------------------------------------------------------------
// Implicit-GEMM conv1d (K=3 SAME) via mfma_f32_32x32x16_bf16, pipelined.
// Input:  xh bf16 [B][TH][CP] (halo rows zero). Weights: wb bf16 [3][CP][CP].
// Block: 256 thr / 4 waves; tile M=256 t x N=64 co; wave: 64 t x 64 co.
// Fused epilogue: bias + residual + bf16 store + BN partial sums (s1,s2)
// reduced per block and atomically added into p1/p2[b][co] (exactly two
// commutative contributors per slot -> deterministic).
// Grid: 2560 1-D blocks, chunked-XCD swizzled so all 10 blocks of one b
// (5 co-tiles x 2 t-tiles) land on the same XCD -> X fetched once per b.
// ---------------------------------------------------------------------------
template<int HAS_RES>
__global__ __launch_bounds__(256, 3) void conv_mfma(
    const u16* __restrict__ xh,
    const u16* __restrict__ wb,
    const float* __restrict__ bias,
    const u16* __restrict__ res,     // halo layout [B][TH][CP] (conv input)
    u16* __restrict__ outp,          // bf16 [B][T][CP] pre-BN y
    float* __restrict__ p1,
    float* __restrict__ p2)
{
    __shared__ u16 Xs[258][XPAD];
    __shared__ u16 Ws[3][64][XPAD];

    const int tid = threadIdx.x;
    // chunked XCD swizzle: 2560 = 8 * 320, bijective
    const u32 bid = blockIdx.x;
    const u32 lin = (bid & 7u) * 320u + (bid >> 3);
    const int b   = (int)(lin / 10u);
    const int r10 = (int)(lin - (u32)b * 10u);
    const int co0 = (r10 >> 1) * 64;
    const int t0  = (r10 & 1) * 256;

    const int lane = tid & 63;
    const int wv   = tid >> 6;
    const int l31  = lane & 31;
    const int kb8  = (lane >> 5) * 8;
    const int rofs = (lane >> 5) * 4;

    f32x16 acc[2][2];
    #pragma unroll
    for (int mi = 0; mi < 2; ++mi)
        #pragma unroll
        for (int ni = 0; ni < 2; ++ni)
            #pragma unroll
            for (int r = 0; r < 16; ++r) acc[mi][ni][r] = 0.f;

    const u16* xbase = xh + ((size_t)b * TH + t0) * CP;   // local row 0 = Xh row t0
    const int xr = tid >> 2;
    const int xc = (tid & 3) * 8;

    uint4 xg[5];
    uint4 wg[3];

    auto loadChunk = [&](int ci0) {
        #pragma unroll
        for (int s = 0; s < 4; ++s)
            xg[s] = *(const uint4*)(xbase + (size_t)(s * 64 + xr) * CP + ci0 + xc);
        if (tid < 8)
            xg[4] = *(const uint4*)(xbase + (size_t)(256 + xr) * CP + ci0 + xc);
        #pragma unroll
        for (int s = 0; s < 3; ++s) {
            const int i = tid + s * 256;
            const int tap = i >> 8, co = (i & 255) >> 2, q = i & 3;
            wg[s] = *(const uint4*)(wb + ((size_t)tap * CP + co0 + co) * CP + ci0 + q * 8);
        }
    };
    auto storeChunk = [&]() {
        #pragma unroll
        for (int s = 0; s < 4; ++s)
            *(uint4*)&Xs[s * 64 + xr][xc] = xg[s];
        if (tid < 8)
            *(uint4*)&Xs[256 + xr][xc] = xg[4];
        #pragma unroll
        for (int s = 0; s < 3; ++s) {
            const int i = tid + s * 256;
            const int tap = i >> 8, co = (i & 255) >> 2, q = i & 3;
            *(uint4*)&Ws[tap][co][q * 8] = wg[s];
        }
    };

    loadChunk(0);
    for (int ch = 0; ch < 10; ++ch) {
        __syncthreads();
        storeChunk();
        __syncthreads();
        if (ch < 9) loadChunk((ch + 1) * 32);

        #pragma unroll
        for (int ks = 0; ks < 2; ++ks) {
            #pragma unroll
            for (int tap = 0; tap < 3; ++tap) {
                const bf16x8 bw0 = ldfrag(&Ws[tap][l31][ks * 16 + kb8]);
                const bf16x8 bw1 = ldfrag(&Ws[tap][32 + l31][ks * 16 + kb8]);
                #pragma unroll
                for (int mi = 0; mi < 2; ++mi) {
                    const bf16x8 av = ldfrag(&Xs[wv * 64 + mi * 32 + l31 + tap][ks * 16 + kb8]);
                    acc[mi][0] = __builtin_amdgcn_mfma_f32_32x32x16_bf16(av, bw0, acc[mi][0], 0, 0, 0);
                    acc[mi][1] = __builtin_amdgcn_mfma_f32_32x32x16_bf16(av, bw1, acc[mi][1], 0, 0, 0);
                }
            }
        }
    }

    // ---- fused epilogue: bias + residual + bf16 store + BN partial sums
    __syncthreads();                       // LDS free; reuse Xs as reduction pad
    float* red = (float*)&Xs[0][0];        // [ni][j][8][32] = 4 KB
    const int wslot = wv * 2 + (lane >> 5);

    #pragma unroll
    for (int ni = 0; ni < 2; ++ni) {
        const int co = co0 + ni * 32 + l31;
        const float bv = bias[co];
        float s1 = 0.f, s2 = 0.f;
        #pragma unroll
        for (int mi = 0; mi < 2; ++mi) {
            #pragma unroll
            for (int r = 0; r < 16; ++r) {
                const int t = t0 + wv * 64 + mi * 32 + (r & 3) + 8 * (r >> 2) + rofs;
                float v = acc[mi][ni][r] + bv;
                if (HAS_RES) v += bf2f(res[((size_t)b * TH + t + 1) * CP + co]);
                const u16 h = f2bf(v);
                const float vq = bf2f(h);          // stats on the rounded value we store
                s1 += vq;
                s2 = fmaf(vq, vq, s2);
                outp[((size_t)b * T_ + t) * CP + co] = h;
            }
        }
        red[((ni * 2 + 0) * 8 + wslot) * 32 + l31] = s1;
        red[((ni * 2 + 1) * 8 + wslot) * 32 + l31] = s2;
    }
    __syncthreads();
    if (tid < 128) {
        const int ni = tid >> 6, j = (tid >> 5) & 1, c = tid & 31;
        float s = 0.f;
        #pragma unroll
        for (int w = 0; w < 8; ++w) s += red[((ni * 2 + j) * 8 + w) * 32 + c];
        float* dst = j ? p2 : p1;
        atomicAdd(&dst[(size_t)b * COUT + co0 + ni * 32 + c], s);
    }
}

// ---------------------------------------------------------------------------
// finalize: reduce per-b partials per subject -> scale/shift
// ---------------------------------------------------------------------------
__global__ void finalize_kernel(
    const float* __restrict__ p1, const float* __restrict__ p2,
    const int* __restrict__ subj,
    const float* __restrict__ gamma, const float* __restrict__ beta,
    float* __restrict__ scale, float* __restrict__ shift)
{
    const int idx = blockIdx.x * blockDim.x + threadIdx.x;
    if (idx >= NSUBJ * COUT) return;
    const int s = idx / COUT;
    const int c = idx - s * COUT;
    float s1 = 0.f, s2 = 0.f; int nb = 0;
    for (int b = 0; b < B_; ++b) {
        if (subj[b] == s) {
            s1 += p1[(size_t)b * COUT + c];
            s2 += p2[(size_t)b * COUT + c];
            ++nb;
        }
    }
    const float cnt  = fmaxf((float)nb * (float)T_, 1.0f);
    const float mean = s1 / cnt;
    const float var  = s2 / cnt - mean * mean;
    const float sc = gamma[idx] * (1.0f / sqrtf(var + 1e-5f));
    scale[idx] = sc;
    shift[idx] = beta[idx] - mean * sc;
}

// BN+GELU: y bf16 plain [b][t][c] -> act bf16 halo layout [b][1+t][c]
__global__ __launch_bounds__(256) void bn_gelu_b2b(
    const u16* __restrict__ x, const int* __restrict__ subj,
    const float* __restrict__ scale, const float* __restrict__ shift,
    u16* __restrict__ out)
{
    const u32 base = ((u32)blockIdx.x * 256u + (u32)threadIdx.x) * 8u;
    const u32 b = base / ((u32)T_ * CP);
    const u32 r = base - b * ((u32)T_ * CP);
    const u32 t = r / CP;
    const u32 c = r - t * CP;
    const int s = subj[b];
    const uint4 u = *(const uint4*)(x + base);
    const float* scp = scale + (size_t)s * COUT + c;
    const float* shp = shift + (size_t)s * COUT + c;
    const float4 sca = *(const float4*)(scp);
    const float4 scb = *(const float4*)(scp + 4);
    const float4 sha = *(const float4*)(shp);
    const float4 shb = *(const float4*)(shp + 4);
    const float scv[8] = {sca.x, sca.y, sca.z, sca.w, scb.x, scb.y, scb.z, scb.w};
    const float shv[8] = {sha.x, sha.y, sha.z, sha.w, shb.x, shb.y, shb.z, shb.w};
    const u32 w[4] = {u.x, u.y, u.z, u.w};
    u16 o[8];
    #pragma unroll
    for (int k = 0; k < 4; ++k) {
        const float2 f = bfp2(w[k]);
        o[2 * k]     = f2bf(gelu_exact(f.x * scv[2 * k]     + shv[2 * k]));
        o[2 * k + 1] = f2bf(gelu_exact(f.y * scv[2 * k + 1] + shv[2 * k + 1]));
    }
    u16* op = out + ((size_t)b * TH + 1 + t) * CP + c;
    *(uint4*)op = *(const uint4*)o;
}

// final: BN+GELU + transpose [b][t][c] bf16 plain -> [b][c][t] fp32 (d_out)
__global__ __launch_bounds__(256) void final_tr(
    const u16* __restrict__ x, const int* __restrict__ subj,
    const float* __restrict__ scale, const float* __restrict__ shift,
    float* __restrict__ out)
{
    __shared__ float Lt[64][65];
    const int t0 = blockIdx.x * 64, c0 = blockIdx.y * 64, b = blockIdx.z;
    const int s = subj[b];
    {
        const int tt = threadIdx.x >> 2, chs = (threadIdx.x & 3) * 16;
        const u16* xp = x + ((size_t)b * T_ + t0 + tt) * COUT + c0 + chs;
        const uint4 u0 = *(const uint4*)xp;
        const uint4 u1 = *(const uint4*)(xp + 8);
        const u32 wd[8] = {u0.x, u0.y, u0.z, u0.w, u1.x, u1.y, u1.z, u1.w};
        const float* scp = scale + (size_t)s * COUT + c0 + chs;
        const float* shp = shift + (size_t)s * COUT + c0 + chs;
        #pragma unroll
        for (int k = 0; k < 8; ++k) {
            const float2 f = bfp2(wd[k]);
            Lt[tt][chs + 2 * k]     = gelu_exact(f.x * scp[2 * k]     + shp[2 * k]);
            Lt[tt][chs + 2 * k + 1] = gelu_exact(f.y * scp[2 * k + 1] + shp[2 * k + 1]);
        }
    }
    __syncthreads();
    {
        const int cr = threadIdx.x >> 2, tch = (threadIdx.x & 3) * 16;
        float* op = out + ((size_t)b * COUT + c0 + cr) * T_ + t0 + tch;
        #pragma unroll
        for (int k = 0; k < 16; k += 4)
            *(float4*)(op + k) = make_float4(Lt[tch + k][cr], Lt[tch + k + 1][cr],
                                             Lt[tch + k + 2][cr], Lt[tch + k + 3][cr]);
    }
}

// ---------------------------------------------------------------------------

extern "C" void kernel_launch(void* const* d_in, const int* in_sizes, int n_in,
                              void* d_out, int out_size, void* d_ws, size_t ws_size,
                              hipStream_t stream) {
    const float* X    = (const float*)d_in[0];
    const int*   subj = (const int*)d_in[1];
    const float* w0   = (const float*)d_in[2];
    const float* b0   = (const float*)d_in[3];
    const float* w1   = (const float*)d_in[4];
    const float* b1   = (const float*)d_in[5];
    const float* w2   = (const float*)d_in[6];
    const float* b2   = (const float*)d_in[7];
    const float* g0   = (const float*)d_in[8];
    const float* be0  = (const float*)d_in[9];
    const float* g1   = (const float*)d_in[10];
    const float* be1  = (const float*)d_in[11];
    const float* g2   = (const float*)d_in[12];
    const float* be2  = (const float*)d_in[13];

    // ws layout (total 170,608,640 B — identical footprint to previous version)
    const size_t actElems = (size_t)B_ * TH * CP;      // 42,106,880  (84.21 MB)
    const size_t yElems   = (size_t)B_ * T_ * CP;      // 41,943,040  (83.89 MB)
    u16* act  = (u16*)d_ws;
    u16* y    = act + actElems;
    u16* wb0  = y + yElems;
    u16* wb1  = wb0 + 3 * CP * CP;
    u16* wb2  = wb1 + 3 * CP * CP;
    float* p1 = (float*)(wb2 + 3 * CP * CP);           // [B_][COUT]
    float* p2 = p1 + (size_t)B_ * COUT;                // [B_][COUT]
    float* sc = p2 + (size_t)B_ * COUT;
    float* sh = sc + NSUBJ * COUT;

    const dim3 cgrid(2560);                // conv: 2 t-tiles x 5 co-tiles x 256 b (swizzled 1-D)
    const dim3 pgrid(8, 5, B_);            // prep_x / final_tr tiles
    const int  agrid = (int)(((size_t)B_ * T_ * CP) / 8 / 256);   // 20480
    const int  wgrid = (3 * CP * CP + 255) / 256;                 // 1200
    const int  zgrid = (2 * B_ * COUT) / 4 / 256;                 // 160

    // ---- preparation
    prep_w<<<wgrid, 256, 0, stream>>>(w0, wb0, 271);
    prep_w<<<wgrid, 256, 0, stream>>>(w1, wb1, 320);
    prep_w<<<wgrid, 256, 0, stream>>>(w2, wb2, 320);
    zero_halo<<<80, 256, 0, stream>>>(act);
    prep_x<<<pgrid, 256, 0, stream>>>(X, act);

    // ---- layer 0
    zero_p<<<zgrid, 256, 0, stream>>>((float4*)p1);
    conv_mfma<0><<<cgrid, 256, 0, stream>>>(act, wb0, b0, act, y, p1, p2);
    finalize_kernel<<<5, 256, 0, stream>>>(p1, p2, subj, g0, be0, sc, sh);
    bn_gelu_b2b<<<agrid, 256, 0, stream>>>(y, subj, sc, sh, act);

    // ---- layer 1 (residual)
    zero_p<<<zgrid, 256, 0, stream>>>((float4*)p1);
    conv_mfma<1><<<cgrid, 256, 0, stream>>>(act, wb1, b1, act, y, p1, p2);
    finalize_kernel<<<5, 256, 0, stream>>>(p1, p2, subj, g1, be1, sc, sh);
    bn_gelu_b2b<<<agrid, 256, 0, stream>>>(y, subj, sc, sh, act);

    // ---- layer 2 (residual)
    zero_p<<<zgrid, 256, 0, stream>>>((float4*)p1);
    conv_mfma<1><<<cgrid, 256, 0, stream>>>(act, wb2, b2, act, y, p1, p2);
    finalize_kernel<<<5, 256, 0, stream>>>(p1, p2, subj, g2, be2, sc, sh);
    final_tr<<<pgrid, 256, 0, stream>>>(y, subj, sc, sh, (float*)d_out);
}